// Round 4
// baseline (213.301 us; speedup 1.0000x reference)
//
#include <hip/hip_runtime.h>
#include <stdint.h>

#define Bsz  8192
#define DMOD 512
#define NE   4
#define NP   1024
#define NF   2048
#define BM   256
#define BN   128
#define BK   64

typedef float  f32x4  __attribute__((ext_vector_type(4)));
typedef __bf16 bf16x8 __attribute__((ext_vector_type(8)));
typedef unsigned short u16x8 __attribute__((ext_vector_type(8)));

typedef __attribute__((address_space(3))) void       lds_void;
typedef const __attribute__((address_space(1))) void glb_void;
#define GLOAD16(gp, lp) \
  __builtin_amdgcn_global_load_lds((glb_void*)(gp), (lds_void*)(lp), 16, 0, 0)

__device__ __forceinline__ unsigned short f32_bf16(float f) {
  unsigned int u = __float_as_uint(f);
  u += 0x7FFFu + ((u >> 16) & 1u);   // round-to-nearest-even
  return (unsigned short)(u >> 16);
}

// ---------------- kernel 1: concat + cvt + fused gate (softmax/top2) ----------------
__global__ __launch_bounds__(256) void fuse_gate(
    const float* __restrict__ x0, const float* __restrict__ x1,
    const float* __restrict__ x2, const float* __restrict__ x3,
    const float* __restrict__ Wg,
    unsigned short* __restrict__ fusedB, float* __restrict__ gw,
    double* __restrict__ lossAcc)
{
  __shared__ float sred[4][4];
  const int b   = blockIdx.x;
  const int tid = threadIdx.x;
  const int f   = tid * 8;
  const float* xm  = (f < 1024) ? (f < 512 ? x0 : x1) : (f < 1536 ? x2 : x3);
  const float* src = xm + (size_t)b * DMOD + (f & 511);
  float4 v0 = *(const float4*)src;
  float4 v1 = *(const float4*)(src + 4);
  u16x8 o;
  o[0] = f32_bf16(v0.x); o[1] = f32_bf16(v0.y); o[2] = f32_bf16(v0.z); o[3] = f32_bf16(v0.w);
  o[4] = f32_bf16(v1.x); o[5] = f32_bf16(v1.y); o[6] = f32_bf16(v1.z); o[7] = f32_bf16(v1.w);
  *(u16x8*)(fusedB + (size_t)b * NF + f) = o;

  float d[4];
  #pragma unroll
  for (int e = 0; e < 4; ++e) {
    const float* w = Wg + e * NF + f;
    d[e] = v0.x * w[0] + v0.y * w[1] + v0.z * w[2] + v0.w * w[3]
         + v1.x * w[4] + v1.y * w[5] + v1.z * w[6] + v1.w * w[7];
  }
  #pragma unroll
  for (int off = 32; off; off >>= 1) {
    #pragma unroll
    for (int e = 0; e < 4; ++e) d[e] += __shfl_xor(d[e], off);
  }
  if ((tid & 63) == 0) {
    #pragma unroll
    for (int e = 0; e < 4; ++e) sred[tid >> 6][e] = d[e];
  }
  __syncthreads();
  if (tid == 0) {
    float a0 = sred[0][0] + sred[1][0] + sred[2][0] + sred[3][0];
    float a1 = sred[0][1] + sred[1][1] + sred[2][1] + sred[3][1];
    float a2 = sred[0][2] + sred[1][2] + sred[2][2] + sred[3][2];
    float a3 = sred[0][3] + sred[1][3] + sred[2][3] + sred[3][3];
    float m  = fmaxf(fmaxf(a0, a1), fmaxf(a2, a3));
    float e0 = expf(a0 - m), e1 = expf(a1 - m), e2 = expf(a2 - m), e3 = expf(a3 - m);
    float inv = 1.f / (e0 + e1 + e2 + e3);
    float p0 = e0 * inv, p1 = e1 * inv, p2 = e2 * inv, p3 = e3 * inv;
    int i1 = 0; float b1 = a0;
    if (a1 > b1) { b1 = a1; i1 = 1; }
    if (a2 > b1) { b1 = a2; i1 = 2; }
    if (a3 > b1) { b1 = a3; i1 = 3; }
    int i2 = -1; float b2 = -3.4e38f;
    if (i1 != 0 && a0 > b2) { b2 = a0; i2 = 0; }
    if (i1 != 1 && a1 > b2) { b2 = a1; i2 = 1; }
    if (i1 != 2 && a2 > b2) { b2 = a2; i2 = 2; }
    if (i1 != 3 && a3 > b2) { b2 = a3; i2 = 3; }
    gw[(size_t)b * 4 + 0] = (i1 == 0 || i2 == 0) ? p0 : 0.f;
    gw[(size_t)b * 4 + 1] = (i1 == 1 || i2 == 1) ? p1 : 0.f;
    gw[(size_t)b * 4 + 2] = (i1 == 2 || i2 == 2) ? p2 : 0.f;
    gw[(size_t)b * 4 + 3] = (i1 == 3 || i2 == 3) ? p3 : 0.f;
    if (b == 0) *lossAcc = 0.0;
  }
}

// ---------------- kernel 2: We [E][F][P] f32 -> We_T [E][P][F] bf16 ----------------
__global__ __launch_bounds__(256) void we_transpose(
    const float* __restrict__ We, unsigned short* __restrict__ WeT)
{
  __shared__ float t[64][65];
  const int e  = blockIdx.z;
  const int tf = blockIdx.x * 64;
  const int tp = blockIdx.y * 64;
  const int t4 = threadIdx.x * 4;
  const float* src = We + ((size_t)e * NF + tf) * NP + tp;
  #pragma unroll
  for (int i = 0; i < 4; ++i) {
    int li = i * 1024 + t4;
    int r = li >> 6, c = li & 63;
    float4 v = *(const float4*)(src + (size_t)r * NP + c);
    t[c][r] = v.x; t[c+1][r] = v.y; t[c+2][r] = v.z; t[c+3][r] = v.w;
  }
  __syncthreads();
  unsigned short* dst = WeT + ((size_t)e * NP + tp) * NF + tf;
  #pragma unroll
  for (int i = 0; i < 4; ++i) {
    int li = i * 1024 + t4;
    int r = li >> 6, c = li & 63;
    ushort4 o;
    o.x = f32_bf16(t[r][c]);   o.y = f32_bf16(t[r][c+1]);
    o.z = f32_bf16(t[r][c+2]); o.w = f32_bf16(t[r][c+3]);
    *(ushort4*)(dst + (size_t)r * NF + c) = o;
  }
}

// ---------------- kernel 3: 8-wave 256x128 deep-pipelined per-expert GEMM ----------------
// Depth-3 LDS ring (stage t+3 into just-freed buffer -> 2 K-steps of load cover),
// counted vmcnt(12) (never drained in-loop), raw s_barrier, per-K-step 2-phase
// MFMA clusters wrapped in s_setprio (T5), XCD-chunked block swizzle (T1),
// XOR-swizzled LDS via inverse-swizzled global source (T2, rule #21).
__global__ __launch_bounds__(512, 2) void moe_gemm(
    const unsigned short* __restrict__ fusedB,   // [B][F] bf16
    const unsigned short* __restrict__ WeT,      // [E][P][F] bf16
    const float* __restrict__ gw,                // [B][E]
    const float* __restrict__ be,                // [E][P]
    const float* __restrict__ label,             // [B][P]
    float* __restrict__ out,                     // [0]=loss, [1..] preds
    double* __restrict__ lossAcc)
{
  __shared__ __align__(16) unsigned short As[3][BM * BK];  // 96 KiB
  __shared__ __align__(16) unsigned short Bs[3][BN * BK];  // 48 KiB
  __shared__ float gwS[BM][4];
  __shared__ float red[8];

  const int tid  = threadIdx.x;
  const int l    = tid & 63;
  const int wave = tid >> 6;      // 0..7
  const int wr   = wave >> 1;     // 0..3 (M)
  const int wc   = wave & 1;      // 0..1 (N)
  const int lrow = l & 15;
  const int g4   = l >> 4;
  const int lr8  = l >> 3;
  const int lc8  = l & 7;
  const int schA = lc8 ^ lr8;                 // inverse-swizzled source chunk (lane-const)
  const int ch0  = ((g4    ) ^ (l & 7)) * 8;  // read chunk, ks=0 (lane-const)
  const int ch1  = ((g4 + 4) ^ (l & 7)) * 8;  // read chunk, ks=1

  // XCD-chunked swizzle: XCD c gets 32 consecutive logical tiles =
  // 4 row-panels x 8 cols -> A working set 4MB = one L2.
  const int bid  = (int)blockIdx.x;
  const int swz  = (bid & 7) * 32 + (bid >> 3);
  const int brow = (swz >> 3) * BM;
  const int pcol = (swz & 7) * BN;

  if (tid < BM) *(float4*)gwS[tid] = *(const float4*)(gw + (size_t)(brow + tid) * 4);
  __syncthreads();

  f32x4 accT[4][4], accE[4][4];
  #pragma unroll
  for (int m = 0; m < 4; ++m)
    #pragma unroll
    for (int n = 0; n < 4; ++n) {
      accT[m][n] = f32x4{0.f, 0.f, 0.f, 0.f};
      accE[m][n] = f32x4{0.f, 0.f, 0.f, 0.f};
    }

  // stage flat step t (expert = t>>5, k-tile = t&31): 6 GLOAD16 per wave
  auto STAGE = [&](int t, unsigned short* Ad, unsigned short* Bd) {
    const int e  = t >> 5;
    const int k0 = (t & 31) << 6;
    const unsigned short* Ag = fusedB + (size_t)brow * NF + k0;
    const unsigned short* Bg = WeT + ((size_t)e * NP + pcol) * NF + k0;
    #pragma unroll
    for (int i = 0; i < 4; ++i) {
      const int r0 = i * 64 + wave * 8;
      GLOAD16(Ag + (size_t)(r0 + lr8) * NF + schA * 8, (char*)(Ad + r0 * BK));
    }
    #pragma unroll
    for (int i = 0; i < 2; ++i) {
      const int r0 = i * 64 + wave * 8;
      GLOAD16(Bg + (size_t)(r0 + lr8) * NF + schA * 8, (char*)(Bd + r0 * BK));
    }
  };

  auto FOLD = [&](int e) {   // accT += w[row,e]*accE; accE = 0 (register-only)
    #pragma unroll
    for (int m = 0; m < 4; ++m)
      #pragma unroll
      for (int r = 0; r < 4; ++r) {
        const float wv = gwS[wr * 64 + m * 16 + g4 * 4 + r][e];
        #pragma unroll
        for (int n = 0; n < 4; ++n) {
          accT[m][n][r] += wv * accE[m][n][r];
          accE[m][n][r] = 0.f;
        }
      }
  };

  unsigned short *A0 = As[0], *A1 = As[1], *A2 = As[2];
  unsigned short *B0 = Bs[0], *B1 = Bs[1], *B2 = Bs[2];

  STAGE(0, A0, B0);
  STAGE(1, A1, B1);
  STAGE(2, A2, B2);   // 18 loads in flight

  #pragma unroll 1
  for (int t = 0; t < 128; ++t) {
    // vmcnt ledger: outstanding batches {t, t+1, t+2} (6 loads each) for t<126.
    if (t < 126)       asm volatile("s_waitcnt vmcnt(12)" ::: "memory");
    else if (t == 126) asm volatile("s_waitcnt vmcnt(6)"  ::: "memory");
    else               asm volatile("s_waitcnt vmcnt(0)"  ::: "memory");
    __builtin_amdgcn_s_barrier();          // all waves' batch-t loads landed
    __builtin_amdgcn_sched_barrier(0);     // pin ds_reads after the ready-barrier

    // ---- phase A: read all B-frags + A-frags m0,m1; 16 MFMA ----
    bf16x8 b0[4], b1[4];
    #pragma unroll
    for (int n = 0; n < 4; ++n) {
      const unsigned short* bp = B0 + (wc * 64 + n * 16 + lrow) * BK;
      b0[n] = __builtin_bit_cast(bf16x8, *(const u16x8*)(bp + ch0));
      b1[n] = __builtin_bit_cast(bf16x8, *(const u16x8*)(bp + ch1));
    }
    bf16x8 aA[2][2];
    #pragma unroll
    for (int m = 0; m < 2; ++m) {
      const unsigned short* ap = A0 + (wr * 64 + m * 16 + lrow) * BK;
      aA[m][0] = __builtin_bit_cast(bf16x8, *(const u16x8*)(ap + ch0));
      aA[m][1] = __builtin_bit_cast(bf16x8, *(const u16x8*)(ap + ch1));
    }
    asm volatile("s_waitcnt lgkmcnt(0)" ::: "memory");
    __builtin_amdgcn_s_setprio(1);
    #pragma unroll
    for (int m = 0; m < 2; ++m)
      #pragma unroll
      for (int n = 0; n < 4; ++n) {
        accE[m][n] = __builtin_amdgcn_mfma_f32_16x16x32_bf16(aA[m][0], b0[n], accE[m][n], 0, 0, 0);
        accE[m][n] = __builtin_amdgcn_mfma_f32_16x16x32_bf16(aA[m][1], b1[n], accE[m][n], 0, 0, 0);
      }
    __builtin_amdgcn_s_setprio(0);
    __builtin_amdgcn_s_barrier();          // phase cadence (role-split for setprio)

    // ---- phase B: A-frags m2,m3; 16 MFMA ----
    bf16x8 aB[2][2];
    #pragma unroll
    for (int m = 0; m < 2; ++m) {
      const unsigned short* ap = A0 + (wr * 64 + (m + 2) * 16 + lrow) * BK;
      aB[m][0] = __builtin_bit_cast(bf16x8, *(const u16x8*)(ap + ch0));
      aB[m][1] = __builtin_bit_cast(bf16x8, *(const u16x8*)(ap + ch1));
    }
    asm volatile("s_waitcnt lgkmcnt(0)" ::: "memory");
    __builtin_amdgcn_s_setprio(1);
    #pragma unroll
    for (int m = 0; m < 2; ++m)
      #pragma unroll
      for (int n = 0; n < 4; ++n) {
        accE[m + 2][n] = __builtin_amdgcn_mfma_f32_16x16x32_bf16(aB[m][0], b0[n], accE[m + 2][n], 0, 0, 0);
        accE[m + 2][n] = __builtin_amdgcn_mfma_f32_16x16x32_bf16(aB[m][1], b1[n], accE[m + 2][n], 0, 0, 0);
      }
    __builtin_amdgcn_s_setprio(0);
    if ((t & 31) == 31) FOLD(t >> 5);

    __builtin_amdgcn_sched_barrier(0);     // all reads of buf-t complete (lgkmcnt above)
    __builtin_amdgcn_s_barrier();          // every wave done with buf t
    __builtin_amdgcn_sched_barrier(0);     // keep STAGE after the barrier
    if (t < 125) STAGE(t + 3, A0, B0);     // overwrite the just-freed buffer
    unsigned short* ta = A0; A0 = A1; A1 = A2; A2 = ta;
    unsigned short* tb = B0; B0 = B1; B1 = B2; B2 = tb;
  }

  // epilogue: bias, store preds, fused MSE partial
  float lsum = 0.f;
  #pragma unroll
  for (int m = 0; m < 4; ++m) {
    #pragma unroll
    for (int r = 0; r < 4; ++r) {
      const int lrowi = wr * 64 + m * 16 + g4 * 4 + r;
      const int grow  = brow + lrowi;
      const float w0 = gwS[lrowi][0];
      const float w1 = gwS[lrowi][1];
      const float w2 = gwS[lrowi][2];
      const float w3 = gwS[lrowi][3];
      #pragma unroll
      for (int n = 0; n < 4; ++n) {
        const int gcol = pcol + wc * 64 + n * 16 + lrow;
        float bias = w0 * be[gcol] + w1 * be[NP + gcol] + w2 * be[2 * NP + gcol] + w3 * be[3 * NP + gcol];
        float pred = accT[m][n][r] + bias;
        out[1 + (size_t)grow * NP + gcol] = pred;
        float d = pred - label[(size_t)grow * NP + gcol];
        lsum += d * d;
      }
    }
  }
  #pragma unroll
  for (int off = 32; off; off >>= 1) lsum += __shfl_xor(lsum, off);
  if (l == 0) red[wave] = lsum;
  __syncthreads();
  if (tid == 0) {
    double s = 0.0;
    #pragma unroll
    for (int w = 0; w < 8; ++w) s += (double)red[w];
    atomicAdd(lossAcc, s);
  }
}

// ---------------- kernel 4: finalize loss ----------------
__global__ void finalize_kernel(const double* __restrict__ lossAcc, float* __restrict__ out) {
  out[0] = (float)(*lossAcc * (1.0 / ((double)Bsz * (double)NP)));
}

extern "C" void kernel_launch(void* const* d_in, const int* in_sizes, int n_in,
                              void* d_out, int out_size, void* d_ws, size_t ws_size,
                              hipStream_t stream) {
  const float* x0    = (const float*)d_in[0];
  const float* x1    = (const float*)d_in[1];
  const float* x2    = (const float*)d_in[2];
  const float* x3    = (const float*)d_in[3];
  const float* label = (const float*)d_in[4];
  const float* Wg    = (const float*)d_in[5];
  const float* We    = (const float*)d_in[6];
  const float* be    = (const float*)d_in[7];
  float* out = (float*)d_out;

  char* ws = (char*)d_ws;
  unsigned short* WeT    = (unsigned short*)ws;                         // 16 MiB
  unsigned short* fusedB = (unsigned short*)(ws + ((size_t)16 << 20));  // 32 MiB
  float*  gw      = (float*)(ws + ((size_t)48 << 20));                  // 128 KiB
  double* lossAcc = (double*)(ws + ((size_t)49 << 20));                 // 8 B

  fuse_gate<<<dim3(Bsz), 256, 0, stream>>>(x0, x1, x2, x3, Wg, fusedB, gw, lossAcc);
  we_transpose<<<dim3(NF / 64, NP / 64, NE), 256, 0, stream>>>(We, WeT);
  moe_gemm<<<dim3(256), 512, 0, stream>>>(fusedB, WeT, gw, be, label, out, lossAcc);
  finalize_kernel<<<1, 1, 0, stream>>>(lossAcc, out);
}